// Round 8
// baseline (495.498 us; speedup 1.0000x reference)
//
#include <hip/hip_runtime.h>
#include <hip/hip_bf16.h>

#define S_LEN 2048
#define HID   4096
#define NH    32
#define HD    128
#define KD    4096

typedef __attribute__((ext_vector_type(4))) float f32x4;
typedef __attribute__((ext_vector_type(8))) short s16x8;
typedef __attribute__((ext_vector_type(4))) short s16x4;

#define AS1 __attribute__((address_space(1)))
#define AS3 __attribute__((address_space(3)))

__device__ __forceinline__ void gl_lds16(const void* g, void* l) {
  __builtin_amdgcn_global_load_lds((const AS1 void*)g, (AS3 void*)l, 16, 0, 0);
}

__device__ inline short f2bf(float f) {
  union { float f; unsigned u; } v; v.f = f;
  return (short)((v.u + 0x7fffu + ((v.u >> 16) & 1u)) >> 16);
}
__device__ inline float bf2f(short s) {
  union { unsigned u; float f; } v; v.u = ((unsigned)(unsigned short)s) << 16;
  return v.f;
}
__device__ inline unsigned packbf(float a, float b) {
  return (unsigned)(unsigned short)f2bf(a) | ((unsigned)(unsigned short)f2bf(b) << 16);
}

// ============ one-time converts ============
__global__ __launch_bounds__(256)
void cvt_kernel(const float* __restrict__ A, short* __restrict__ Ab) {
  const size_t i = ((size_t)blockIdx.x * 256 + threadIdx.x) * 8;
  f32x4 v0 = *(const f32x4*)&A[i];
  f32x4 v1 = *(const f32x4*)&A[i + 4];
  s16x8 r;
  r[0]=f2bf(v0[0]); r[1]=f2bf(v0[1]); r[2]=f2bf(v0[2]); r[3]=f2bf(v0[3]);
  r[4]=f2bf(v1[0]); r[5]=f2bf(v1[1]); r[6]=f2bf(v1[2]); r[7]=f2bf(v1[3]);
  *(s16x8*)&Ab[i] = r;
}

// W [KD][N] f32 -> Wt [N][KD] bf16
__global__ __launch_bounds__(256)
void transcvt_kernel(const float* __restrict__ W, short* __restrict__ Wt, const int N) {
  __shared__ float tile[64][65];
  const int k0 = blockIdx.x * 64, n0 = blockIdx.y * 64;
  const int t = threadIdx.x;
#pragma unroll
  for (int i = 0; i < 16; ++i) {
    const int e = i * 256 + t;
    const int k = e >> 6, n = e & 63;
    tile[n][k] = W[(size_t)(k0 + k) * N + n0 + n];
  }
  __syncthreads();
  const int nn = t >> 2, ks = (t & 3) * 16;
  s16x8 a, b;
#pragma unroll
  for (int i = 0; i < 8; i++) a[i] = f2bf(tile[nn][ks + i]);
#pragma unroll
  for (int i = 0; i < 8; i++) b[i] = f2bf(tile[nn][ks + 8 + i]);
  *(s16x8*)&Wt[(size_t)(n0 + nn) * KD + k0 + ks]     = a;
  *(s16x8*)&Wt[(size_t)(n0 + nn) * KD + k0 + ks + 8] = b;
}

// ============ gemm5 (QKV): BM=256 BN=128, 4 waves, wave 128x64, ring-3, counted vmcnt ====
template<int EPI>
__global__ __launch_bounds__(256, 2)
void gemm5_kernel(const short* __restrict__ A, const short* __restrict__ Bt,
                  const float* __restrict__ bias,
                  short* __restrict__ Qb, short* __restrict__ Kb, short* __restrict__ Vb,
                  float* __restrict__ Cout)
{
  __shared__ char sm[3][24576] __attribute__((aligned(128)));
  const int KD2 = KD * 2;
  const int bid = blockIdx.x;
  const int xcd = bid & 7, idx = bid >> 3;
  const int m0 = (idx & 7) * 256;
  const int n0 = (xcd * ((EPI == 0) ? 12 : 4) + (idx >> 3)) * 128;

  const int t = threadIdx.x, lane = t & 63, c = lane & 15, g = lane >> 4;
  const int w = t >> 6, wr = w >> 1, wc = w & 1;
  const int flip = ((c >> 1) & 7) << 4;
  const int laneA = wr * 8192 + ((c * 64 + g * 16) ^ flip);
  const int laneB = 16384 + wc * 4096 + ((c * 64 + g * 16) ^ flip);

  const char* srcA[4];
  const char* srcB[2];
#pragma unroll
  for (int j = 0; j < 4; ++j) {
    const int la = j * 4096 + t * 16;
    const int ls = la ^ ((la >> 3) & 0x70);
    srcA[j] = (const char*)A + (size_t)(m0 + (ls >> 6)) * KD2 + (ls & 63);
  }
#pragma unroll
  for (int j = 0; j < 2; ++j) {
    const int la = j * 4096 + t * 16;
    const int ls = la ^ ((la >> 3) & 0x70);
    srcB[j] = (const char*)Bt + (size_t)(n0 + (ls >> 6)) * KD2 + (ls & 63);
  }

  f32x4 acc[8][4];
#pragma unroll
  for (int i = 0; i < 8; i++)
#pragma unroll
    for (int j = 0; j < 4; j++) acc[i][j] = (f32x4){0.f, 0.f, 0.f, 0.f};

#define STG(S, H) do {                                        \
    const size_t ko_ = (size_t)(H) * 64;                      \
    gl_lds16(srcA[0] + ko_, sm[S] + t * 16);                  \
    gl_lds16(srcA[1] + ko_, sm[S] + 4096  + t * 16);          \
    gl_lds16(srcA[2] + ko_, sm[S] + 8192  + t * 16);          \
    gl_lds16(srcA[3] + ko_, sm[S] + 12288 + t * 16);          \
    gl_lds16(srcB[0] + ko_, sm[S] + 16384 + t * 16);          \
    gl_lds16(srcB[1] + ko_, sm[S] + 20480 + t * 16);          \
  } while (0)

#define COMP(S) do {                                                       \
    const char* b_ = sm[S];                                                \
    s16x8 a_[8], bb_[4];                                                   \
    _Pragma("unroll")                                                      \
    for (int mi = 0; mi < 8; ++mi) a_[mi] = *(const s16x8*)(b_ + laneA + mi * 1024); \
    _Pragma("unroll")                                                      \
    for (int ni = 0; ni < 4; ++ni) bb_[ni] = *(const s16x8*)(b_ + laneB + ni * 1024); \
    __builtin_amdgcn_s_setprio(1);                                         \
    _Pragma("unroll")                                                      \
    for (int mi = 0; mi < 8; ++mi)                                         \
      _Pragma("unroll")                                                    \
      for (int ni = 0; ni < 4; ++ni)                                       \
        acc[mi][ni] = __builtin_amdgcn_mfma_f32_16x16x32_bf16(a_[mi], bb_[ni], acc[mi][ni], 0, 0, 0); \
    __builtin_amdgcn_s_setprio(0);                                         \
  } while (0)

#define WAIT6 asm volatile("s_waitcnt vmcnt(6)" ::: "memory")
#define WAIT0 asm volatile("s_waitcnt vmcnt(0)" ::: "memory")
#define BARR  do { __builtin_amdgcn_s_barrier(); asm volatile("" ::: "memory"); } while (0)

  STG(0, 0); STG(1, 1);
  for (int j = 0; j < 42; ++j) {
    const int h = 3 * j;
    WAIT6; BARR; STG(2, h + 2); COMP(0);
    WAIT6; BARR; STG(0, h + 3); COMP(1);
    WAIT6; BARR; STG(1, h + 4); COMP(2);
  }
  WAIT6; BARR; COMP(0);
  WAIT0; BARR; COMP(1);

#undef STG
#undef COMP
#undef WAIT6
#undef WAIT0
#undef BARR

  if (EPI == 0) {
#pragma unroll
    for (int ni = 0; ni < 4; ++ni) {
      const int ncol = n0 + wc * 64 + ni * 16 + c;
      const int which = ncol >> 12;
      const int h = (ncol >> 7) & 31;
      const int dcl = ncol & 127;
      short* dst = (which == 0) ? Qb : ((which == 1) ? Kb : Vb);
      const float bv = bias[ncol];
#pragma unroll
      for (int mi = 0; mi < 8; ++mi)
#pragma unroll
        for (int jj = 0; jj < 4; ++jj) {
          const int row = m0 + wr * 128 + mi * 16 + g * 4 + jj;
          dst[((size_t)h * S_LEN + row) * HD + dcl] = f2bf(acc[mi][ni][jj] + bv);
        }
    }
  } else {
#pragma unroll
    for (int ni = 0; ni < 4; ++ni) {
      const int ncol = n0 + wc * 64 + ni * 16 + c;
#pragma unroll
      for (int mi = 0; mi < 8; ++mi)
#pragma unroll
        for (int jj = 0; jj < 4; ++jj) {
          const int row = m0 + wr * 128 + mi * 16 + g * 4 + jj;
          Cout[(size_t)row * HID + ncol] = acc[mi][ni][jj];
        }
    }
  }
}

// ============ gemm7 (O-proj): BM=128 BN=128, 4 waves, wave 64x64, ring-3 16KB slots ====
// 512 blocks all-resident (3 blocks/CU, 12 waves/CU). A bf16 [M][KD], Bt bf16 [HID][KD].
__global__ __launch_bounds__(256, 3)
void gemm7_kernel(const short* __restrict__ A, const short* __restrict__ Bt,
                  float* __restrict__ Cout)
{
  __shared__ char sm[3][16384] __attribute__((aligned(128)));
  const int KD2 = KD * 2;
  const int bid = blockIdx.x;
  const int xcd = bid & 7, idx = bid >> 3;      // 512 = 8 xcd * 64
  const int m0 = (idx & 15) * 128;
  const int n0 = (xcd * 4 + (idx >> 4)) * 128;

  const int t = threadIdx.x, lane = t & 63, c = lane & 15, g = lane >> 4;
  const int w = t >> 6, wr = w >> 1, wc = w & 1;
  const int flip = ((c >> 1) & 7) << 4;
  const int laneA = wr * 4096 + ((c * 64 + g * 16) ^ flip);
  const int laneB = 8192 + wc * 4096 + ((c * 64 + g * 16) ^ flip);

  const char* srcA[2];
  const char* srcB[2];
#pragma unroll
  for (int j = 0; j < 2; ++j) {
    const int la = j * 4096 + t * 16;
    const int ls = la ^ ((la >> 3) & 0x70);
    srcA[j] = (const char*)A  + (size_t)(m0 + (ls >> 6)) * KD2 + (ls & 63);
    srcB[j] = (const char*)Bt + (size_t)(n0 + (ls >> 6)) * KD2 + (ls & 63);
  }

  f32x4 acc[4][4];
#pragma unroll
  for (int i = 0; i < 4; i++)
#pragma unroll
    for (int j = 0; j < 4; j++) acc[i][j] = (f32x4){0.f, 0.f, 0.f, 0.f};

#define STG7(S, H) do {                                       \
    const size_t ko_ = (size_t)(H) * 64;                      \
    gl_lds16(srcA[0] + ko_, sm[S] + t * 16);                  \
    gl_lds16(srcA[1] + ko_, sm[S] + 4096  + t * 16);          \
    gl_lds16(srcB[0] + ko_, sm[S] + 8192  + t * 16);          \
    gl_lds16(srcB[1] + ko_, sm[S] + 12288 + t * 16);          \
  } while (0)

#define COMP7(S) do {                                                      \
    const char* b_ = sm[S];                                                \
    s16x8 a_[4], bb_[4];                                                   \
    _Pragma("unroll")                                                      \
    for (int mi = 0; mi < 4; ++mi) a_[mi] = *(const s16x8*)(b_ + laneA + mi * 1024); \
    _Pragma("unroll")                                                      \
    for (int ni = 0; ni < 4; ++ni) bb_[ni] = *(const s16x8*)(b_ + laneB + ni * 1024); \
    __builtin_amdgcn_s_setprio(1);                                         \
    _Pragma("unroll")                                                      \
    for (int mi = 0; mi < 4; ++mi)                                         \
      _Pragma("unroll")                                                    \
      for (int ni = 0; ni < 4; ++ni)                                       \
        acc[mi][ni] = __builtin_amdgcn_mfma_f32_16x16x32_bf16(a_[mi], bb_[ni], acc[mi][ni], 0, 0, 0); \
    __builtin_amdgcn_s_setprio(0);                                         \
  } while (0)

#define WAIT4 asm volatile("s_waitcnt vmcnt(4)" ::: "memory")
#define WAIT0 asm volatile("s_waitcnt vmcnt(0)" ::: "memory")
#define BARR  do { __builtin_amdgcn_s_barrier(); asm volatile("" ::: "memory"); } while (0)

  STG7(0, 0); STG7(1, 1);
  for (int j = 0; j < 42; ++j) {
    const int h = 3 * j;
    WAIT4; BARR; STG7(2, h + 2); COMP7(0);
    WAIT4; BARR; STG7(0, h + 3); COMP7(1);
    WAIT4; BARR; STG7(1, h + 4); COMP7(2);
  }
  WAIT4; BARR; COMP7(0);
  WAIT0; BARR; COMP7(1);

#undef STG7
#undef COMP7
#undef WAIT4
#undef WAIT0
#undef BARR

#pragma unroll
  for (int ni = 0; ni < 4; ++ni) {
    const int ncol = n0 + wc * 64 + ni * 16 + c;
#pragma unroll
    for (int mi = 0; mi < 4; ++mi)
#pragma unroll
      for (int jj = 0; jj < 4; ++jj) {
        const int row = m0 + wr * 64 + mi * 16 + g * 4 + jj;
        Cout[(size_t)row * HID + ncol] = acc[mi][ni][jj];
      }
  }
}

// ============ fallback GEMM (reg-staged) ============
template<int EPI, int ABF16>
__global__ __launch_bounds__(256)
void gemm_kernel(const void* __restrict__ Av, const float* __restrict__ B,
                 const float* __restrict__ bias, const int N,
                 short* __restrict__ Qb, short* __restrict__ Kb, short* __restrict__ Vb,
                 float* __restrict__ Cout)
{
  __shared__ short As[128][40];
  __shared__ short Bs[128][40];
  const int m0 = blockIdx.x * 128;
  const int nb = blockIdx.y * 128;
  const int t  = threadIdx.x;
  const int w = t >> 6, lane = t & 63, c = lane & 15, g = lane >> 4;
  const int wm = (w >> 1) * 64, wn = (w & 1) * 64;

  f32x4 acc[4][4];
#pragma unroll
  for (int i = 0; i < 4; i++)
#pragma unroll
    for (int j = 0; j < 4; j++) acc[i][j] = (f32x4){0.f, 0.f, 0.f, 0.f};

  const int ar = t >> 3;
  const int ac = (t & 7) * 4;
  const int bn = t & 127;
  const int bkq = (t >> 7) * 16;

  for (int k0 = 0; k0 < KD; k0 += 32) {
#pragma unroll
    for (int rr = 0; rr < 4; rr++) {
      const int row = rr * 32 + ar;
      if (ABF16) {
        *(s16x4*)&As[row][ac] =
          *(const s16x4*)((const short*)Av + (size_t)(m0 + row) * KD + k0 + ac);
      } else {
        f32x4 v = *(const f32x4*)((const float*)Av + (size_t)(m0 + row) * KD + k0 + ac);
        s16x4 pk;
        pk[0] = f2bf(v[0]); pk[1] = f2bf(v[1]); pk[2] = f2bf(v[2]); pk[3] = f2bf(v[3]);
        *(s16x4*)&As[row][ac] = pk;
      }
    }
    const float* pB = B + (size_t)(k0 + bkq) * N + nb + bn;
    s16x8 b0, b1;
#pragma unroll
    for (int i = 0; i < 8; i++) b0[i] = f2bf(pB[(size_t)i * N]);
#pragma unroll
    for (int i = 0; i < 8; i++) b1[i] = f2bf(pB[(size_t)(i + 8) * N]);
    *(s16x8*)&Bs[bn][bkq]     = b0;
    *(s16x8*)&Bs[bn][bkq + 8] = b1;
    __syncthreads();
    s16x8 af[4], bfr[4];
#pragma unroll
    for (int i = 0; i < 4; i++) af[i]  = *(const s16x8*)&As[wm + i * 16 + c][g * 8];
#pragma unroll
    for (int i = 0; i < 4; i++) bfr[i] = *(const s16x8*)&Bs[wn + i * 16 + c][g * 8];
#pragma unroll
    for (int mi = 0; mi < 4; mi++)
#pragma unroll
      for (int ni = 0; ni < 4; ni++)
        acc[mi][ni] = __builtin_amdgcn_mfma_f32_16x16x32_bf16(af[mi], bfr[ni], acc[mi][ni], 0, 0, 0);
    __syncthreads();
  }

  if (EPI == 0) {
    const int which = nb >> 12;
    const int h = (nb & 4095) >> 7;
    short* dst = (which == 0) ? Qb : ((which == 1) ? Kb : Vb);
#pragma unroll
    for (int ni = 0; ni < 4; ni++) {
      const int d = wn + ni * 16 + c;
      const float bv = bias[nb + d];
#pragma unroll
      for (int mi = 0; mi < 4; mi++)
#pragma unroll
        for (int j = 0; j < 4; j++) {
          const int row = m0 + wm + mi * 16 + g * 4 + j;
          dst[((size_t)h * S_LEN + row) * HD + d] = f2bf(acc[mi][ni][j] + bv);
        }
    }
  } else {
#pragma unroll
    for (int ni = 0; ni < 4; ni++) {
      const int n = nb + wn + ni * 16 + c;
#pragma unroll
      for (int mi = 0; mi < 4; mi++)
#pragma unroll
        for (int j = 0; j < 4; j++) {
          const int row = m0 + wm + mi * 16 + g * 4 + j;
          Cout[(size_t)row * N + n] = acc[mi][ni][j];
        }
    }
  }
}

// ============ RoPE ============
__global__ void rope_kernel(const int* __restrict__ positions,
                            short* __restrict__ Qb, short* __restrict__ Kb)
{
  const int s = blockIdx.x;
  const int h = blockIdx.y * 4 + threadIdx.y;
  const int d = threadIdx.x;
  const float pos = (float)positions[s];
  const float inv_freq = exp2f(-(float)d * 0.20762050593046014f);
  const float ang = pos * inv_freq;
  float sn, cs;
  sincosf(ang, &sn, &cs);
  const size_t base = ((size_t)h * S_LEN + s) * HD + d;
  const float scale = 0.08838834764831845f;
  float x1 = bf2f(Qb[base]), x2 = bf2f(Qb[base + 64]);
  Qb[base]      = f2bf((x1 * cs - x2 * sn) * scale);
  Qb[base + 64] = f2bf((x2 * cs + x1 * sn) * scale);
  x1 = bf2f(Kb[base]); x2 = bf2f(Kb[base + 64]);
  Kb[base]      = f2bf(x1 * cs - x2 * sn);
  Kb[base + 64] = f2bf(x2 * cs + x1 * sn);
}

// ============ V -> Vt [NH][HD][S] ============
__global__ __launch_bounds__(256)
void vtrans_kernel(const short* __restrict__ V, short* __restrict__ Vt)
{
  __shared__ short tile[64][72];
  const int h = blockIdx.z;
  const int s0 = blockIdx.x * 64;
  const int d0 = blockIdx.y * 64;
  const int tx = threadIdx.x & 63, ty = threadIdx.x >> 6;
  for (int r = ty; r < 64; r += 4)
    tile[r][tx] = V[((size_t)h * S_LEN + s0 + r) * HD + d0 + tx];
  __syncthreads();
  for (int r = ty; r < 64; r += 4)
    Vt[((size_t)h * HD + d0 + r) * S_LEN + s0 + tx] = tile[tx][r];
}

// ============ causal flash attention v3: swapped QK^T, in-register P, KVBLK=64 ============
__global__ __launch_bounds__(512)
void attn_kernel(const short* __restrict__ Q, const short* __restrict__ Kg,
                 const short* __restrict__ Vtg, short* __restrict__ attn_out)
{
  __shared__ short Ks[2][64][128];
  __shared__ short Vs[2][128][72];
  const int h = blockIdx.y;
  const int q0 = blockIdx.x * 128;
  const int t = threadIdx.x;
  const int w = t >> 6, lane = t & 63, c = lane & 15, g = lane >> 4;
  const short* Qh = Q   + (size_t)h * S_LEN * HD;
  const short* Kh = Kg  + (size_t)h * S_LEN * HD;
  const short* Vh = Vtg + (size_t)h * HD * S_LEN;

  const int krow = t >> 4, kch = t & 15;
  const int vrow = t >> 3, vch = t & 7;
  const int ksw = (kch ^ ((krow & 3) | ((krow >> 1) & 4))) * 16;

  const int rbase = (c >> 2) * 8 + (c & 3);
  const int sb = (rbase & 3) | ((rbase >> 1) & 4);
  int koff[4];
#pragma unroll
  for (int di = 0; di < 4; ++di) koff[di] = ((di * 4 + g) ^ sb) * 16;

  const int qg = q0 + w * 16 + c;
  s16x8 qf[4];
#pragma unroll
  for (int di = 0; di < 4; di++)
    qf[di] = *(const s16x8*)&Qh[(size_t)qg * HD + di * 32 + g * 8];

  f32x4 o[8];
#pragma unroll
  for (int dt = 0; dt < 8; dt++) o[dt] = (f32x4){0.f, 0.f, 0.f, 0.f};
  float m_r = -3.0e38f, l_r = 0.f;

  const int nt = q0 / 64 + 2;

  {
#pragma unroll
    for (int i = 0; i < 2; ++i) {
      s16x8 gK = *(const s16x8*)&Kh[(size_t)(i * 32 + krow) * HD + kch * 8];
      s16x8 gV = *(const s16x8*)&Vh[(size_t)(i * 64 + vrow) * S_LEN + vch * 8];
      *(s16x8*)((char*)&Ks[0][0][0] + (i * 32 + krow) * 256 + ksw) = gK;
      *(s16x8*)&Vs[0][i * 64 + vrow][vch * 8] = gV;
    }
  }
  __syncthreads();

  for (int kt = 0; kt < nt; kt++) {
    const int cur = kt & 1;
    const int kb = kt * 64;
    s16x8 gK0, gK1, gV0, gV1;
    if (kt + 1 < nt) {
      gK0 = *(const s16x8*)&Kh[(size_t)(kb + 64 + krow) * HD + kch * 8];
      gK1 = *(const s16x8*)&Kh[(size_t)(kb + 96 + krow) * HD + kch * 8];
      gV0 = *(const s16x8*)&Vh[(size_t)vrow * S_LEN + kb + 64 + vch * 8];
      gV1 = *(const s16x8*)&Vh[(size_t)(64 + vrow) * S_LEN + kb + 64 + vch * 8];
    }
    f32x4 sA = (f32x4){0,0,0,0}, sB = (f32x4){0,0,0,0};
    f32x4 sC = (f32x4){0,0,0,0}, sD = (f32x4){0,0,0,0};
    const char* kb_ = (const char*)&Ks[cur][0][0] + rbase * 256;
#pragma unroll
    for (int di = 0; di < 4; ++di) {
      const char* p = kb_ + koff[di];
      s16x8 kA = *(const s16x8*)(p);
      s16x8 kB = *(const s16x8*)(p + 1024);
      s16x8 kC = *(const s16x8*)(p + 8192);
      s16x8 kD = *(const s16x8*)(p + 9216);
      sA = __builtin_amdgcn_mfma_f32_16x16x32_bf16(kA, qf[di], sA, 0, 0, 0);
      sB = __builtin_amdgcn_mfma_f32_16x16x32_bf16(kB, qf[di], sB, 0, 0, 0);
      sC = __builtin_amdgcn_mfma_f32_16x16x32_bf16(kC, qf[di], sC, 0, 0, 0);
      sD = __builtin_amdgcn_mfma_f32_16x16x32_bf16(kD, qf[di], sD, 0, 0, 0);
    }
    float v[16];
#pragma unroll
    for (int j = 0; j < 4; ++j) {
      v[j]      = (kb + 8 * g + j      <= qg) ? sA[j] : -__builtin_inff();
      v[4 + j]  = (kb + 8 * g + 4 + j  <= qg) ? sB[j] : -__builtin_inff();
      v[8 + j]  = (kb + 32 + 8 * g + j     <= qg) ? sC[j] : -__builtin_inff();
      v[12 + j] = (kb + 32 + 8 * g + 4 + j <= qg) ? sD[j] : -__builtin_inff();
    }
    float mx = v[0];
#pragma unroll
    for (int i = 1; i < 16; ++i) mx = fmaxf(mx, v[i]);
    mx = fmaxf(mx, __shfl_xor(mx, 16, 64));
    mx = fmaxf(mx, __shfl_xor(mx, 32, 64));
    const float mn = fmaxf(m_r, mx);
    if (!__all(mn - m_r <= 8.0f)) {
      const float al = __expf(m_r - mn);
      l_r *= al;
#pragma unroll
      for (int dt = 0; dt < 8; dt++)
#pragma unroll
        for (int j = 0; j < 4; j++) o[dt][j] *= al;
      m_r = mn;
    }
    float p[16];
    float rs = 0.f;
#pragma unroll
    for (int i = 0; i < 16; ++i) { p[i] = __expf(v[i] - m_r); rs += p[i]; }
    rs += __shfl_xor(rs, 16, 64);
    rs += __shfl_xor(rs, 32, 64);
    l_r += rs;
    union { s16x8 v8; unsigned u[4]; } pb0, pb1;
    pb0.u[0] = packbf(p[0], p[1]);   pb0.u[1] = packbf(p[2], p[3]);
    pb0.u[2] = packbf(p[4], p[5]);   pb0.u[3] = packbf(p[6], p[7]);
    pb1.u[0] = packbf(p[8], p[9]);   pb1.u[1] = packbf(p[10], p[11]);
    pb1.u[2] = packbf(p[12], p[13]); pb1.u[3] = packbf(p[14], p[15]);
#pragma unroll
    for (int dt = 0; dt < 8; dt++) {
      s16x8 vf0 = *(const s16x8*)&Vs[cur][dt * 16 + c][g * 8];
      s16x8 vf1 = *(const s16x8*)&Vs[cur][dt * 16 + c][32 + g * 8];
      o[dt] = __builtin_amdgcn_mfma_f32_16x16x32_bf16(vf0, pb0.v8, o[dt], 0, 0, 0);
      o[dt] = __builtin_amdgcn_mfma_f32_16x16x32_bf16(vf1, pb1.v8, o[dt], 0, 0, 0);
    }
    __syncthreads();
    if (kt + 1 < nt) {
      *(s16x8*)((char*)&Ks[cur ^ 1][0][0] + krow * 256 + ksw)        = gK0;
      *(s16x8*)((char*)&Ks[cur ^ 1][0][0] + (32 + krow) * 256 + ksw) = gK1;
      *(s16x8*)&Vs[cur ^ 1][vrow][vch * 8]      = gV0;
      *(s16x8*)&Vs[cur ^ 1][64 + vrow][vch * 8] = gV1;
    }
    __syncthreads();
  }

  const float inv_l = 1.0f / l_r;
#pragma unroll
  for (int dt = 0; dt < 8; dt++) {
    s16x4 pk;
#pragma unroll
    for (int j = 0; j < 4; j++) pk[j] = f2bf(o[dt][j] * inv_l);
    *(s16x4*)&attn_out[(size_t)qg * HID + h * HD + dt * 16 + g * 4] = pk;
  }
}

extern "C" void kernel_launch(void* const* d_in, const int* in_sizes, int n_in,
                              void* d_out, int out_size, void* d_ws, size_t ws_size,
                              hipStream_t stream)
{
  const int*   positions = (const int*)d_in[0];
  const float* hidden    = (const float*)d_in[1];
  const float* w_qkv     = (const float*)d_in[2];
  const float* b_qkv     = (const float*)d_in[3];
  const float* w_o       = (const float*)d_in[4];
  float* out = (float*)d_out;

  char* ws = (char*)d_ws;
  const size_t MB = (size_t)1 << 20;

  if (ws_size >= 224 * MB) {
    short* Ah    = (short*)(ws);                 // 16 MB  bf16 [S][KD]
    short* Wqt   = (short*)(ws + 16 * MB);       // 96 MB  bf16 [3*HID][KD]
    short* Wot   = (short*)(ws + 112 * MB);      // 32 MB  bf16 [HID][KD]
    short* Qb    = (short*)(ws + 144 * MB);      // 16 MB
    short* Kb    = (short*)(ws + 160 * MB);      // 16 MB
    short* Vb    = (short*)(ws + 176 * MB);      // 16 MB
    short* Vt    = (short*)(ws + 192 * MB);      // 16 MB
    short* attnb = (short*)(ws + 208 * MB);      // 16 MB  bf16 [S][HID]

    cvt_kernel<<<4096, 256, 0, stream>>>(hidden, Ah);
    transcvt_kernel<<<dim3(KD / 64, 3 * HID / 64), 256, 0, stream>>>(w_qkv, Wqt, 3 * HID);
    transcvt_kernel<<<dim3(KD / 64, HID / 64), 256, 0, stream>>>(w_o, Wot, HID);
    gemm5_kernel<0><<<768, 256, 0, stream>>>(Ah, Wqt, b_qkv, Qb, Kb, Vb, nullptr);
    rope_kernel<<<dim3(S_LEN, NH / 4), dim3(64, 4), 0, stream>>>(positions, Qb, Kb);
    vtrans_kernel<<<dim3(S_LEN / 64, HD / 64, NH), 256, 0, stream>>>(Vb, Vt);
    attn_kernel<<<dim3(S_LEN / 128, NH), 512, 0, stream>>>(Qb, Kb, Vt, attnb);
    gemm7_kernel<<<512, 256, 0, stream>>>(attnb, Wot, out);
  } else {
    short* Qb    = (short*)(ws);
    short* Kb    = (short*)(ws + 16 * MB);
    short* Vb    = (short*)(ws + 32 * MB);
    short* Vt    = (short*)(ws + 48 * MB);
    short* attnb = (short*)(ws + 64 * MB);

    gemm_kernel<0, 0><<<dim3(16, 96), 256, 0, stream>>>(hidden, w_qkv, b_qkv, 3 * HID,
                                                        Qb, Kb, Vb, nullptr);
    rope_kernel<<<dim3(S_LEN, NH / 4), dim3(64, 4), 0, stream>>>(positions, Qb, Kb);
    vtrans_kernel<<<dim3(S_LEN / 64, HD / 64, NH), 256, 0, stream>>>(Vb, Vt);
    attn_kernel<<<dim3(S_LEN / 128, NH), 512, 0, stream>>>(Qb, Kb, Vt, attnb);
    gemm_kernel<1, 1><<<dim3(16, 32), 256, 0, stream>>>(attnb, w_o, nullptr, HID,
                                                        nullptr, nullptr, nullptr, out);
  }
}

// Round 10
// 469.762 us; speedup vs baseline: 1.0548x; 1.0548x over previous
//
#include <hip/hip_runtime.h>
#include <hip/hip_bf16.h>

#define S_LEN 2048
#define HID   4096
#define NH    32
#define HD    128
#define KD    4096

typedef __attribute__((ext_vector_type(4))) float f32x4;
typedef __attribute__((ext_vector_type(8))) short s16x8;
typedef __attribute__((ext_vector_type(4))) short s16x4;

#define AS1 __attribute__((address_space(1)))
#define AS3 __attribute__((address_space(3)))

__device__ __forceinline__ void gl_lds16(const void* g, void* l) {
  __builtin_amdgcn_global_load_lds((const AS1 void*)g, (AS3 void*)l, 16, 0, 0);
}

__device__ inline short f2bf(float f) {
  union { float f; unsigned u; } v; v.f = f;
  return (short)((v.u + 0x7fffu + ((v.u >> 16) & 1u)) >> 16);
}
__device__ inline float bf2f(short s) {
  union { unsigned u; float f; } v; v.u = ((unsigned)(unsigned short)s) << 16;
  return v.f;
}
__device__ inline unsigned packbf(float a, float b) {
  return (unsigned)(unsigned short)f2bf(a) | ((unsigned)(unsigned short)f2bf(b) << 16);
}

// ============ one-time converts ============
__global__ __launch_bounds__(256)
void cvt_kernel(const float* __restrict__ A, short* __restrict__ Ab) {
  const size_t i = ((size_t)blockIdx.x * 256 + threadIdx.x) * 8;
  f32x4 v0 = *(const f32x4*)&A[i];
  f32x4 v1 = *(const f32x4*)&A[i + 4];
  s16x8 r;
  r[0]=f2bf(v0[0]); r[1]=f2bf(v0[1]); r[2]=f2bf(v0[2]); r[3]=f2bf(v0[3]);
  r[4]=f2bf(v1[0]); r[5]=f2bf(v1[1]); r[6]=f2bf(v1[2]); r[7]=f2bf(v1[3]);
  *(s16x8*)&Ab[i] = r;
}

// W [KD][N] f32 -> Wt [N][KD] bf16
__global__ __launch_bounds__(256)
void transcvt_kernel(const float* __restrict__ W, short* __restrict__ Wt, const int N) {
  __shared__ float tile[64][65];
  const int k0 = blockIdx.x * 64, n0 = blockIdx.y * 64;
  const int t = threadIdx.x;
#pragma unroll
  for (int i = 0; i < 16; ++i) {
    const int e = i * 256 + t;
    const int k = e >> 6, n = e & 63;
    tile[n][k] = W[(size_t)(k0 + k) * N + n0 + n];
  }
  __syncthreads();
  const int nn = t >> 2, ks = (t & 3) * 16;
  s16x8 a, b;
#pragma unroll
  for (int i = 0; i < 8; i++) a[i] = f2bf(tile[nn][ks + i]);
#pragma unroll
  for (int i = 0; i < 8; i++) b[i] = f2bf(tile[nn][ks + 8 + i]);
  *(s16x8*)&Wt[(size_t)(n0 + nn) * KD + k0 + ks]     = a;
  *(s16x8*)&Wt[(size_t)(n0 + nn) * KD + k0 + ks + 8] = b;
}

// ============ gemm5 (QKV): BM=256 BN=128, 4 waves, wave 128x64, ring-3, counted vmcnt ====
template<int EPI>
__global__ __launch_bounds__(256, 2)
void gemm5_kernel(const short* __restrict__ A, const short* __restrict__ Bt,
                  const float* __restrict__ bias,
                  short* __restrict__ Qb, short* __restrict__ Kb, short* __restrict__ Vb,
                  float* __restrict__ Cout)
{
  __shared__ char sm[3][24576] __attribute__((aligned(128)));
  const int KD2 = KD * 2;
  const int bid = blockIdx.x;
  const int xcd = bid & 7, idx = bid >> 3;
  const int m0 = (idx & 7) * 256;
  const int n0 = (xcd * ((EPI == 0) ? 12 : 4) + (idx >> 3)) * 128;

  const int t = threadIdx.x, lane = t & 63, c = lane & 15, g = lane >> 4;
  const int w = t >> 6, wr = w >> 1, wc = w & 1;
  const int flip = ((c >> 1) & 7) << 4;
  const int laneA = wr * 8192 + ((c * 64 + g * 16) ^ flip);
  const int laneB = 16384 + wc * 4096 + ((c * 64 + g * 16) ^ flip);

  const char* srcA[4];
  const char* srcB[2];
#pragma unroll
  for (int j = 0; j < 4; ++j) {
    const int la = j * 4096 + t * 16;
    const int ls = la ^ ((la >> 3) & 0x70);
    srcA[j] = (const char*)A + (size_t)(m0 + (ls >> 6)) * KD2 + (ls & 63);
  }
#pragma unroll
  for (int j = 0; j < 2; ++j) {
    const int la = j * 4096 + t * 16;
    const int ls = la ^ ((la >> 3) & 0x70);
    srcB[j] = (const char*)Bt + (size_t)(n0 + (ls >> 6)) * KD2 + (ls & 63);
  }

  f32x4 acc[8][4];
#pragma unroll
  for (int i = 0; i < 8; i++)
#pragma unroll
    for (int j = 0; j < 4; j++) acc[i][j] = (f32x4){0.f, 0.f, 0.f, 0.f};

#define STG(S, H) do {                                        \
    const size_t ko_ = (size_t)(H) * 64;                      \
    gl_lds16(srcA[0] + ko_, sm[S] + t * 16);                  \
    gl_lds16(srcA[1] + ko_, sm[S] + 4096  + t * 16);          \
    gl_lds16(srcA[2] + ko_, sm[S] + 8192  + t * 16);          \
    gl_lds16(srcA[3] + ko_, sm[S] + 12288 + t * 16);          \
    gl_lds16(srcB[0] + ko_, sm[S] + 16384 + t * 16);          \
    gl_lds16(srcB[1] + ko_, sm[S] + 20480 + t * 16);          \
  } while (0)

#define COMP(S) do {                                                       \
    const char* b_ = sm[S];                                                \
    s16x8 a_[8], bb_[4];                                                   \
    _Pragma("unroll")                                                      \
    for (int mi = 0; mi < 8; ++mi) a_[mi] = *(const s16x8*)(b_ + laneA + mi * 1024); \
    _Pragma("unroll")                                                      \
    for (int ni = 0; ni < 4; ++ni) bb_[ni] = *(const s16x8*)(b_ + laneB + ni * 1024); \
    __builtin_amdgcn_s_setprio(1);                                         \
    _Pragma("unroll")                                                      \
    for (int mi = 0; mi < 8; ++mi)                                         \
      _Pragma("unroll")                                                    \
      for (int ni = 0; ni < 4; ++ni)                                       \
        acc[mi][ni] = __builtin_amdgcn_mfma_f32_16x16x32_bf16(a_[mi], bb_[ni], acc[mi][ni], 0, 0, 0); \
    __builtin_amdgcn_s_setprio(0);                                         \
  } while (0)

#define WAIT6 asm volatile("s_waitcnt vmcnt(6)" ::: "memory")
#define WAIT0 asm volatile("s_waitcnt vmcnt(0)" ::: "memory")
#define BARR  do { __builtin_amdgcn_s_barrier(); asm volatile("" ::: "memory"); } while (0)

  STG(0, 0); STG(1, 1);
  for (int j = 0; j < 42; ++j) {
    const int h = 3 * j;
    WAIT6; BARR; STG(2, h + 2); COMP(0);
    WAIT6; BARR; STG(0, h + 3); COMP(1);
    WAIT6; BARR; STG(1, h + 4); COMP(2);
  }
  WAIT6; BARR; COMP(0);
  WAIT0; BARR; COMP(1);

#undef STG
#undef COMP
#undef WAIT6
#undef WAIT0
#undef BARR

  if (EPI == 0) {
#pragma unroll
    for (int ni = 0; ni < 4; ++ni) {
      const int ncol = n0 + wc * 64 + ni * 16 + c;
      const int which = ncol >> 12;
      const int h = (ncol >> 7) & 31;
      const int dcl = ncol & 127;
      short* dst = (which == 0) ? Qb : ((which == 1) ? Kb : Vb);
      const float bv = bias[ncol];
#pragma unroll
      for (int mi = 0; mi < 8; ++mi)
#pragma unroll
        for (int jj = 0; jj < 4; ++jj) {
          const int row = m0 + wr * 128 + mi * 16 + g * 4 + jj;
          dst[((size_t)h * S_LEN + row) * HD + dcl] = f2bf(acc[mi][ni][jj] + bv);
        }
    }
  } else {
#pragma unroll
    for (int ni = 0; ni < 4; ++ni) {
      const int ncol = n0 + wc * 64 + ni * 16 + c;
#pragma unroll
      for (int mi = 0; mi < 8; ++mi)
#pragma unroll
        for (int jj = 0; jj < 4; ++jj) {
          const int row = m0 + wr * 128 + mi * 16 + g * 4 + jj;
          Cout[(size_t)row * HID + ncol] = acc[mi][ni][jj];
        }
    }
  }
}

// ============ gemm7 (O-proj): BM=128 BN=128, 4 waves, wave 64x64, ring-3 16KB slots ====
__global__ __launch_bounds__(256, 3)
void gemm7_kernel(const short* __restrict__ A, const short* __restrict__ Bt,
                  float* __restrict__ Cout)
{
  __shared__ char sm[3][16384] __attribute__((aligned(128)));
  const int KD2 = KD * 2;
  const int bid = blockIdx.x;
  const int xcd = bid & 7, idx = bid >> 3;
  const int m0 = (idx & 15) * 128;
  const int n0 = (xcd * 4 + (idx >> 4)) * 128;

  const int t = threadIdx.x, lane = t & 63, c = lane & 15, g = lane >> 4;
  const int w = t >> 6, wr = w >> 1, wc = w & 1;
  const int flip = ((c >> 1) & 7) << 4;
  const int laneA = wr * 4096 + ((c * 64 + g * 16) ^ flip);
  const int laneB = 8192 + wc * 4096 + ((c * 64 + g * 16) ^ flip);

  const char* srcA[2];
  const char* srcB[2];
#pragma unroll
  for (int j = 0; j < 2; ++j) {
    const int la = j * 4096 + t * 16;
    const int ls = la ^ ((la >> 3) & 0x70);
    srcA[j] = (const char*)A  + (size_t)(m0 + (ls >> 6)) * KD2 + (ls & 63);
    srcB[j] = (const char*)Bt + (size_t)(n0 + (ls >> 6)) * KD2 + (ls & 63);
  }

  f32x4 acc[4][4];
#pragma unroll
  for (int i = 0; i < 4; i++)
#pragma unroll
    for (int j = 0; j < 4; j++) acc[i][j] = (f32x4){0.f, 0.f, 0.f, 0.f};

#define STG7(S, H) do {                                       \
    const size_t ko_ = (size_t)(H) * 64;                      \
    gl_lds16(srcA[0] + ko_, sm[S] + t * 16);                  \
    gl_lds16(srcA[1] + ko_, sm[S] + 4096  + t * 16);          \
    gl_lds16(srcB[0] + ko_, sm[S] + 8192  + t * 16);          \
    gl_lds16(srcB[1] + ko_, sm[S] + 12288 + t * 16);          \
  } while (0)

#define COMP7(S) do {                                                      \
    const char* b_ = sm[S];                                                \
    s16x8 a_[4], bb_[4];                                                   \
    _Pragma("unroll")                                                      \
    for (int mi = 0; mi < 4; ++mi) a_[mi] = *(const s16x8*)(b_ + laneA + mi * 1024); \
    _Pragma("unroll")                                                      \
    for (int ni = 0; ni < 4; ++ni) bb_[ni] = *(const s16x8*)(b_ + laneB + ni * 1024); \
    __builtin_amdgcn_s_setprio(1);                                         \
    _Pragma("unroll")                                                      \
    for (int mi = 0; mi < 4; ++mi)                                         \
      _Pragma("unroll")                                                    \
      for (int ni = 0; ni < 4; ++ni)                                       \
        acc[mi][ni] = __builtin_amdgcn_mfma_f32_16x16x32_bf16(a_[mi], bb_[ni], acc[mi][ni], 0, 0, 0); \
    __builtin_amdgcn_s_setprio(0);                                         \
  } while (0)

#define WAIT4 asm volatile("s_waitcnt vmcnt(4)" ::: "memory")
#define WAIT0 asm volatile("s_waitcnt vmcnt(0)" ::: "memory")
#define BARR  do { __builtin_amdgcn_s_barrier(); asm volatile("" ::: "memory"); } while (0)

  STG7(0, 0); STG7(1, 1);
  for (int j = 0; j < 42; ++j) {
    const int h = 3 * j;
    WAIT4; BARR; STG7(2, h + 2); COMP7(0);
    WAIT4; BARR; STG7(0, h + 3); COMP7(1);
    WAIT4; BARR; STG7(1, h + 4); COMP7(2);
  }
  WAIT4; BARR; COMP7(0);
  WAIT0; BARR; COMP7(1);

#undef STG7
#undef COMP7
#undef WAIT4
#undef WAIT0
#undef BARR

#pragma unroll
  for (int ni = 0; ni < 4; ++ni) {
    const int ncol = n0 + wc * 64 + ni * 16 + c;
#pragma unroll
    for (int mi = 0; mi < 4; ++mi)
#pragma unroll
      for (int jj = 0; jj < 4; ++jj) {
        const int row = m0 + wr * 64 + mi * 16 + g * 4 + jj;
        Cout[(size_t)row * HID + ncol] = acc[mi][ni][jj];
      }
  }
}

// ============ fallback GEMM (reg-staged) ============
template<int EPI, int ABF16>
__global__ __launch_bounds__(256)
void gemm_kernel(const void* __restrict__ Av, const float* __restrict__ B,
                 const float* __restrict__ bias, const int N,
                 short* __restrict__ Qb, short* __restrict__ Kb, short* __restrict__ Vb,
                 float* __restrict__ Cout)
{
  __shared__ short As[128][40];
  __shared__ short Bs[128][40];
  const int m0 = blockIdx.x * 128;
  const int nb = blockIdx.y * 128;
  const int t  = threadIdx.x;
  const int w = t >> 6, lane = t & 63, c = lane & 15, g = lane >> 4;
  const int wm = (w >> 1) * 64, wn = (w & 1) * 64;

  f32x4 acc[4][4];
#pragma unroll
  for (int i = 0; i < 4; i++)
#pragma unroll
    for (int j = 0; j < 4; j++) acc[i][j] = (f32x4){0.f, 0.f, 0.f, 0.f};

  const int ar = t >> 3;
  const int ac = (t & 7) * 4;
  const int bn = t & 127;
  const int bkq = (t >> 7) * 16;

  for (int k0 = 0; k0 < KD; k0 += 32) {
#pragma unroll
    for (int rr = 0; rr < 4; rr++) {
      const int row = rr * 32 + ar;
      if (ABF16) {
        *(s16x4*)&As[row][ac] =
          *(const s16x4*)((const short*)Av + (size_t)(m0 + row) * KD + k0 + ac);
      } else {
        f32x4 v = *(const f32x4*)((const float*)Av + (size_t)(m0 + row) * KD + k0 + ac);
        s16x4 pk;
        pk[0] = f2bf(v[0]); pk[1] = f2bf(v[1]); pk[2] = f2bf(v[2]); pk[3] = f2bf(v[3]);
        *(s16x4*)&As[row][ac] = pk;
      }
    }
    const float* pB = B + (size_t)(k0 + bkq) * N + nb + bn;
    s16x8 b0, b1;
#pragma unroll
    for (int i = 0; i < 8; i++) b0[i] = f2bf(pB[(size_t)i * N]);
#pragma unroll
    for (int i = 0; i < 8; i++) b1[i] = f2bf(pB[(size_t)(i + 8) * N]);
    *(s16x8*)&Bs[bn][bkq]     = b0;
    *(s16x8*)&Bs[bn][bkq + 8] = b1;
    __syncthreads();
    s16x8 af[4], bfr[4];
#pragma unroll
    for (int i = 0; i < 4; i++) af[i]  = *(const s16x8*)&As[wm + i * 16 + c][g * 8];
#pragma unroll
    for (int i = 0; i < 4; i++) bfr[i] = *(const s16x8*)&Bs[wn + i * 16 + c][g * 8];
#pragma unroll
    for (int mi = 0; mi < 4; mi++)
#pragma unroll
      for (int ni = 0; ni < 4; ni++)
        acc[mi][ni] = __builtin_amdgcn_mfma_f32_16x16x32_bf16(af[mi], bfr[ni], acc[mi][ni], 0, 0, 0);
    __syncthreads();
  }

  if (EPI == 0) {
    const int which = nb >> 12;
    const int h = (nb & 4095) >> 7;
    short* dst = (which == 0) ? Qb : ((which == 1) ? Kb : Vb);
#pragma unroll
    for (int ni = 0; ni < 4; ni++) {
      const int d = wn + ni * 16 + c;
      const float bv = bias[nb + d];
#pragma unroll
      for (int mi = 0; mi < 4; mi++)
#pragma unroll
        for (int j = 0; j < 4; j++) {
          const int row = m0 + wm + mi * 16 + g * 4 + j;
          dst[((size_t)h * S_LEN + row) * HD + d] = f2bf(acc[mi][ni][j] + bv);
        }
    }
  } else {
#pragma unroll
    for (int ni = 0; ni < 4; ni++) {
      const int n = nb + wn + ni * 16 + c;
#pragma unroll
      for (int mi = 0; mi < 4; mi++)
#pragma unroll
        for (int j = 0; j < 4; j++) {
          const int row = m0 + wm + mi * 16 + g * 4 + j;
          Cout[(size_t)row * N + n] = acc[mi][ni][j];
        }
    }
  }
}

// ============ RoPE ============
__global__ void rope_kernel(const int* __restrict__ positions,
                            short* __restrict__ Qb, short* __restrict__ Kb)
{
  const int s = blockIdx.x;
  const int h = blockIdx.y * 4 + threadIdx.y;
  const int d = threadIdx.x;
  const float pos = (float)positions[s];
  const float inv_freq = exp2f(-(float)d * 0.20762050593046014f);
  const float ang = pos * inv_freq;
  float sn, cs;
  sincosf(ang, &sn, &cs);
  const size_t base = ((size_t)h * S_LEN + s) * HD + d;
  const float scale = 0.08838834764831845f;
  float x1 = bf2f(Qb[base]), x2 = bf2f(Qb[base + 64]);
  Qb[base]      = f2bf((x1 * cs - x2 * sn) * scale);
  Qb[base + 64] = f2bf((x2 * cs + x1 * sn) * scale);
  x1 = bf2f(Kb[base]); x2 = bf2f(Kb[base + 64]);
  Kb[base]      = f2bf(x1 * cs - x2 * sn);
  Kb[base + 64] = f2bf(x2 * cs + x1 * sn);
}

// ============ V -> Vt [NH][HD][S] ============
__global__ __launch_bounds__(256)
void vtrans_kernel(const short* __restrict__ V, short* __restrict__ Vt)
{
  __shared__ short tile[64][72];
  const int h = blockIdx.z;
  const int s0 = blockIdx.x * 64;
  const int d0 = blockIdx.y * 64;
  const int tx = threadIdx.x & 63, ty = threadIdx.x >> 6;
  for (int r = ty; r < 64; r += 4)
    tile[r][tx] = V[((size_t)h * S_LEN + s0 + r) * HD + d0 + tx];
  __syncthreads();
  for (int r = ty; r < 64; r += 4)
    Vt[((size_t)h * HD + d0 + r) * S_LEN + s0 + tx] = tile[tx][r];
}

// ============ causal flash attention v4: paired q-panels, shared K/V fragments ============
// grid (8, NH). Block i handles panels a = rows [i*128,+128), b = rows [(15-i)*128,+128).
// nt_a + nt_b = 34 for every block -> perfectly balanced, 256 blocks = 1 round.
// Each staged K/V fragment feeds BOTH panels (ds_read:MFMA = 1:2).
__global__ __launch_bounds__(512)
void attn_kernel(const short* __restrict__ Q, const short* __restrict__ Kg,
                 const short* __restrict__ Vtg, short* __restrict__ attn_out)
{
  __shared__ short Ks[2][64][128];
  __shared__ short Vs[2][128][72];
  const int h = blockIdx.y;
  const int ib = blockIdx.x;                 // 0..7
  const int q0a = ib * 128;
  const int q0b = (15 - ib) * 128;
  const int nt0 = 2 * ib + 2;                // panel a tiles
  const int nt1 = 32 - 2 * ib;               // panel b tiles (loop bound)
  const int t = threadIdx.x;
  const int w = t >> 6, lane = t & 63, c = lane & 15, g = lane >> 4;
  const short* Qh = Q   + (size_t)h * S_LEN * HD;
  const short* Kh = Kg  + (size_t)h * S_LEN * HD;
  const short* Vh = Vtg + (size_t)h * HD * S_LEN;

  const int krow = t >> 4, kch = t & 15;
  const int vrow = t >> 3, vch = t & 7;
  const int ksw = (kch ^ ((krow & 3) | ((krow >> 1) & 4))) * 16;

  const int rbase = (c >> 2) * 8 + (c & 3);
  const int sb = (rbase & 3) | ((rbase >> 1) & 4);
  int koff[4];
#pragma unroll
  for (int di = 0; di < 4; ++di) koff[di] = ((di * 4 + g) ^ sb) * 16;

  const int qga = q0a + w * 16 + c;
  const int qgb = q0b + w * 16 + c;
  s16x8 qfa[4], qfb[4];
#pragma unroll
  for (int di = 0; di < 4; di++) {
    qfa[di] = *(const s16x8*)&Qh[(size_t)qga * HD + di * 32 + g * 8];
    qfb[di] = *(const s16x8*)&Qh[(size_t)qgb * HD + di * 32 + g * 8];
  }

  f32x4 oa[8], ob[8];
#pragma unroll
  for (int dt = 0; dt < 8; dt++) {
    oa[dt] = (f32x4){0.f, 0.f, 0.f, 0.f};
    ob[dt] = (f32x4){0.f, 0.f, 0.f, 0.f};
  }
  float m_a = -3.0e38f, l_a = 0.f, m_b = -3.0e38f, l_b = 0.f;

// online-softmax for one panel: scores in SA..SD -> pb0/pb1 packed P frags
#define SM_PANEL(SA, SB, SC, SD, QG, FULL, MR, LR, OARR, PB0, PB1) do {        \
    float v_[16];                                                              \
    if (FULL) {                                                                \
      _Pragma("unroll")                                                        \
      for (int j = 0; j < 4; ++j) {                                            \
        v_[j] = SA[j]; v_[4 + j] = SB[j]; v_[8 + j] = SC[j]; v_[12 + j] = SD[j]; \
      }                                                                        \
    } else {                                                                   \
      _Pragma("unroll")                                                        \
      for (int j = 0; j < 4; ++j) {                                            \
        v_[j]      = (kb + 8 * g + j          <= (QG)) ? SA[j] : -__builtin_inff(); \
        v_[4 + j]  = (kb + 8 * g + 4 + j      <= (QG)) ? SB[j] : -__builtin_inff(); \
        v_[8 + j]  = (kb + 32 + 8 * g + j     <= (QG)) ? SC[j] : -__builtin_inff(); \
        v_[12 + j] = (kb + 32 + 8 * g + 4 + j <= (QG)) ? SD[j] : -__builtin_inff(); \
      }                                                                        \
    }                                                                          \
    float mx_ = v_[0];                                                         \
    _Pragma("unroll")                                                          \
    for (int ii = 1; ii < 16; ++ii) mx_ = fmaxf(mx_, v_[ii]);                  \
    mx_ = fmaxf(mx_, __shfl_xor(mx_, 16, 64));                                 \
    mx_ = fmaxf(mx_, __shfl_xor(mx_, 32, 64));                                 \
    const float mn_ = fmaxf(MR, mx_);                                          \
    if (!__all(mn_ - MR <= 8.0f)) {                                            \
      const float al_ = __expf(MR - mn_);                                      \
      LR *= al_;                                                               \
      _Pragma("unroll")                                                        \
      for (int dt = 0; dt < 8; ++dt)                                           \
        _Pragma("unroll")                                                      \
        for (int j = 0; j < 4; ++j) OARR[dt][j] *= al_;                        \
      MR = mn_;                                                                \
    }                                                                          \
    float p_[16], rs_ = 0.f;                                                   \
    _Pragma("unroll")                                                          \
    for (int ii = 0; ii < 16; ++ii) { p_[ii] = __expf(v_[ii] - MR); rs_ += p_[ii]; } \
    rs_ += __shfl_xor(rs_, 16, 64);                                            \
    rs_ += __shfl_xor(rs_, 32, 64);                                            \
    LR += rs_;                                                                 \
    union { s16x8 v8; unsigned u[4]; } pu0_, pu1_;                             \
    pu0_.u[0] = packbf(p_[0], p_[1]);   pu0_.u[1] = packbf(p_[2], p_[3]);      \
    pu0_.u[2] = packbf(p_[4], p_[5]);   pu0_.u[3] = packbf(p_[6], p_[7]);      \
    pu1_.u[0] = packbf(p_[8], p_[9]);   pu1_.u[1] = packbf(p_[10], p_[11]);    \
    pu1_.u[2] = packbf(p_[12], p_[13]); pu1_.u[3] = packbf(p_[14], p_[15]);    \
    PB0 = pu0_.v8; PB1 = pu1_.v8;                                              \
  } while (0)

  // prologue: stage tile 0 into buf 0
  {
#pragma unroll
    for (int i = 0; i < 2; ++i) {
      s16x8 gK = *(const s16x8*)&Kh[(size_t)(i * 32 + krow) * HD + kch * 8];
      s16x8 gV = *(const s16x8*)&Vh[(size_t)(i * 64 + vrow) * S_LEN + vch * 8];
      *(s16x8*)((char*)&Ks[0][0][0] + (i * 32 + krow) * 256 + ksw) = gK;
      *(s16x8*)&Vs[0][i * 64 + vrow][vch * 8] = gV;
    }
  }
  __syncthreads();

  for (int kt = 0; kt < nt1; kt++) {
    const int cur = kt & 1;
    const int kb = kt * 64;
    const bool do0 = (kt < nt0);
    s16x8 gK0, gK1, gV0, gV1;
    if (kt + 1 < nt1) {
      gK0 = *(const s16x8*)&Kh[(size_t)(kb + 64 + krow) * HD + kch * 8];
      gK1 = *(const s16x8*)&Kh[(size_t)(kb + 96 + krow) * HD + kch * 8];
      gV0 = *(const s16x8*)&Vh[(size_t)vrow * S_LEN + kb + 64 + vch * 8];
      gV1 = *(const s16x8*)&Vh[(size_t)(64 + vrow) * S_LEN + kb + 64 + vch * 8];
    }
    // ---- dual-panel QK^T sharing K fragments ----
    f32x4 bA = (f32x4){0,0,0,0}, bB = (f32x4){0,0,0,0};
    f32x4 bC = (f32x4){0,0,0,0}, bD = (f32x4){0,0,0,0};
    f32x4 aA = (f32x4){0,0,0,0}, aB = (f32x4){0,0,0,0};
    f32x4 aC = (f32x4){0,0,0,0}, aD = (f32x4){0,0,0,0};
    const char* kbase = (const char*)&Ks[cur][0][0] + rbase * 256;
    __builtin_amdgcn_s_setprio(1);
    if (do0) {
#pragma unroll
      for (int di = 0; di < 4; ++di) {
        const char* p = kbase + koff[di];
        s16x8 kA = *(const s16x8*)(p);
        s16x8 kB = *(const s16x8*)(p + 1024);
        s16x8 kC = *(const s16x8*)(p + 8192);
        s16x8 kD = *(const s16x8*)(p + 9216);
        bA = __builtin_amdgcn_mfma_f32_16x16x32_bf16(kA, qfb[di], bA, 0, 0, 0);
        bB = __builtin_amdgcn_mfma_f32_16x16x32_bf16(kB, qfb[di], bB, 0, 0, 0);
        bC = __builtin_amdgcn_mfma_f32_16x16x32_bf16(kC, qfb[di], bC, 0, 0, 0);
        bD = __builtin_amdgcn_mfma_f32_16x16x32_bf16(kD, qfb[di], bD, 0, 0, 0);
        aA = __builtin_amdgcn_mfma_f32_16x16x32_bf16(kA, qfa[di], aA, 0, 0, 0);
        aB = __builtin_amdgcn_mfma_f32_16x16x32_bf16(kB, qfa[di], aB, 0, 0, 0);
        aC = __builtin_amdgcn_mfma_f32_16x16x32_bf16(kC, qfa[di], aC, 0, 0, 0);
        aD = __builtin_amdgcn_mfma_f32_16x16x32_bf16(kD, qfa[di], aD, 0, 0, 0);
      }
    } else {
#pragma unroll
      for (int di = 0; di < 4; ++di) {
        const char* p = kbase + koff[di];
        s16x8 kA = *(const s16x8*)(p);
        s16x8 kB = *(const s16x8*)(p + 1024);
        s16x8 kC = *(const s16x8*)(p + 8192);
        s16x8 kD = *(const s16x8*)(p + 9216);
        bA = __builtin_amdgcn_mfma_f32_16x16x32_bf16(kA, qfb[di], bA, 0, 0, 0);
        bB = __builtin_amdgcn_mfma_f32_16x16x32_bf16(kB, qfb[di], bB, 0, 0, 0);
        bC = __builtin_amdgcn_mfma_f32_16x16x32_bf16(kC, qfb[di], bC, 0, 0, 0);
        bD = __builtin_amdgcn_mfma_f32_16x16x32_bf16(kD, qfb[di], bD, 0, 0, 0);
      }
    }
    __builtin_amdgcn_s_setprio(0);
    // ---- softmax (panel b always; panel a when active) ----
    s16x8 pb0, pb1, pa0, pa1;
    const bool fullb = (kb + 64 <= q0b);
    SM_PANEL(bA, bB, bC, bD, qgb, fullb, m_b, l_b, ob, pb0, pb1);
    if (do0) {
      const bool fulla = (kb + 64 <= q0a);
      SM_PANEL(aA, aB, aC, aD, qga, fulla, m_a, l_a, oa, pa0, pa1);
    }
    // ---- dual-panel PV sharing V fragments ----
    __builtin_amdgcn_s_setprio(1);
    if (do0) {
#pragma unroll
      for (int dt = 0; dt < 8; dt++) {
        s16x8 vf0 = *(const s16x8*)&Vs[cur][dt * 16 + c][g * 8];
        s16x8 vf1 = *(const s16x8*)&Vs[cur][dt * 16 + c][32 + g * 8];
        ob[dt] = __builtin_amdgcn_mfma_f32_16x16x32_bf16(vf0, pb0, ob[dt], 0, 0, 0);
        ob[dt] = __builtin_amdgcn_mfma_f32_16x16x32_bf16(vf1, pb1, ob[dt], 0, 0, 0);
        oa[dt] = __builtin_amdgcn_mfma_f32_16x16x32_bf16(vf0, pa0, oa[dt], 0, 0, 0);
        oa[dt] = __builtin_amdgcn_mfma_f32_16x16x32_bf16(vf1, pa1, oa[dt], 0, 0, 0);
      }
    } else {
#pragma unroll
      for (int dt = 0; dt < 8; dt++) {
        s16x8 vf0 = *(const s16x8*)&Vs[cur][dt * 16 + c][g * 8];
        s16x8 vf1 = *(const s16x8*)&Vs[cur][dt * 16 + c][32 + g * 8];
        ob[dt] = __builtin_amdgcn_mfma_f32_16x16x32_bf16(vf0, pb0, ob[dt], 0, 0, 0);
        ob[dt] = __builtin_amdgcn_mfma_f32_16x16x32_bf16(vf1, pb1, ob[dt], 0, 0, 0);
      }
    }
    __builtin_amdgcn_s_setprio(0);
    __syncthreads();
    if (kt + 1 < nt1) {
      *(s16x8*)((char*)&Ks[cur ^ 1][0][0] + krow * 256 + ksw)        = gK0;
      *(s16x8*)((char*)&Ks[cur ^ 1][0][0] + (32 + krow) * 256 + ksw) = gK1;
      *(s16x8*)&Vs[cur ^ 1][vrow][vch * 8]      = gV0;
      *(s16x8*)&Vs[cur ^ 1][64 + vrow][vch * 8] = gV1;
    }
    __syncthreads();
  }
#undef SM_PANEL

  const float inv_b = 1.0f / l_b;
  const float inv_a = 1.0f / l_a;
#pragma unroll
  for (int dt = 0; dt < 8; dt++) {
    s16x4 pkb, pka;
#pragma unroll
    for (int j = 0; j < 4; j++) {
      pkb[j] = f2bf(ob[dt][j] * inv_b);
      pka[j] = f2bf(oa[dt][j] * inv_a);
    }
    *(s16x4*)&attn_out[(size_t)qgb * HID + h * HD + dt * 16 + g * 4] = pkb;
    *(s16x4*)&attn_out[(size_t)qga * HID + h * HD + dt * 16 + g * 4] = pka;
  }
}

extern "C" void kernel_launch(void* const* d_in, const int* in_sizes, int n_in,
                              void* d_out, int out_size, void* d_ws, size_t ws_size,
                              hipStream_t stream)
{
  const int*   positions = (const int*)d_in[0];
  const float* hidden    = (const float*)d_in[1];
  const float* w_qkv     = (const float*)d_in[2];
  const float* b_qkv     = (const float*)d_in[3];
  const float* w_o       = (const float*)d_in[4];
  float* out = (float*)d_out;

  char* ws = (char*)d_ws;
  const size_t MB = (size_t)1 << 20;

  if (ws_size >= 224 * MB) {
    short* Ah    = (short*)(ws);                 // 16 MB  bf16 [S][KD]
    short* Wqt   = (short*)(ws + 16 * MB);       // 96 MB  bf16 [3*HID][KD]
    short* Wot   = (short*)(ws + 112 * MB);      // 32 MB  bf16 [HID][KD]
    short* Qb    = (short*)(ws + 144 * MB);      // 16 MB
    short* Kb    = (short*)(ws + 160 * MB);      // 16 MB
    short* Vb    = (short*)(ws + 176 * MB);      // 16 MB
    short* Vt    = (short*)(ws + 192 * MB);      // 16 MB
    short* attnb = (short*)(ws + 208 * MB);      // 16 MB  bf16 [S][HID]

    cvt_kernel<<<4096, 256, 0, stream>>>(hidden, Ah);
    transcvt_kernel<<<dim3(KD / 64, 3 * HID / 64), 256, 0, stream>>>(w_qkv, Wqt, 3 * HID);
    transcvt_kernel<<<dim3(KD / 64, HID / 64), 256, 0, stream>>>(w_o, Wot, HID);
    gemm5_kernel<0><<<768, 256, 0, stream>>>(Ah, Wqt, b_qkv, Qb, Kb, Vb, nullptr);
    rope_kernel<<<dim3(S_LEN, NH / 4), dim3(64, 4), 0, stream>>>(positions, Qb, Kb);
    vtrans_kernel<<<dim3(S_LEN / 64, HD / 64, NH), 256, 0, stream>>>(Vb, Vt);
    attn_kernel<<<dim3(8, NH), 512, 0, stream>>>(Qb, Kb, Vt, attnb);
    gemm7_kernel<<<512, 256, 0, stream>>>(attnb, Wot, out);
  } else {
    short* Qb    = (short*)(ws);
    short* Kb    = (short*)(ws + 16 * MB);
    short* Vb    = (short*)(ws + 32 * MB);
    short* Vt    = (short*)(ws + 48 * MB);
    short* attnb = (short*)(ws + 64 * MB);

    gemm_kernel<0, 0><<<dim3(16, 96), 256, 0, stream>>>(hidden, w_qkv, b_qkv, 3 * HID,
                                                        Qb, Kb, Vb, nullptr);
    rope_kernel<<<dim3(S_LEN, NH / 4), dim3(64, 4), 0, stream>>>(positions, Qb, Kb);
    vtrans_kernel<<<dim3(S_LEN / 64, HD / 64, NH), 256, 0, stream>>>(Vb, Vt);
    attn_kernel<<<dim3(8, NH), 512, 0, stream>>>(Qb, Kb, Vt, attnb);
    gemm_kernel<1, 1><<<dim3(16, 32), 256, 0, stream>>>(attnb, w_o, nullptr, HID,
                                                        nullptr, nullptr, nullptr, out);
  }
}

// Round 11
// 467.456 us; speedup vs baseline: 1.0600x; 1.0049x over previous
//
#include <hip/hip_runtime.h>
#include <hip/hip_bf16.h>

#define S_LEN 2048
#define HID   4096
#define NH    32
#define HD    128
#define KD    4096

typedef __attribute__((ext_vector_type(4))) float f32x4;
typedef __attribute__((ext_vector_type(8))) short s16x8;
typedef __attribute__((ext_vector_type(4))) short s16x4;

#define AS1 __attribute__((address_space(1)))
#define AS3 __attribute__((address_space(3)))

__device__ __forceinline__ void gl_lds16(const void* g, void* l) {
  __builtin_amdgcn_global_load_lds((const AS1 void*)g, (AS3 void*)l, 16, 0, 0);
}

__device__ inline short f2bf(float f) {
  union { float f; unsigned u; } v; v.f = f;
  return (short)((v.u + 0x7fffu + ((v.u >> 16) & 1u)) >> 16);
}
__device__ inline float bf2f(short s) {
  union { unsigned u; float f; } v; v.u = ((unsigned)(unsigned short)s) << 16;
  return v.f;
}
__device__ inline unsigned packbf(float a, float b) {
  return (unsigned)(unsigned short)f2bf(a) | ((unsigned)(unsigned short)f2bf(b) << 16);
}

// ============ one-time converts ============
__global__ __launch_bounds__(256)
void cvt_kernel(const float* __restrict__ A, short* __restrict__ Ab) {
  const size_t i = ((size_t)blockIdx.x * 256 + threadIdx.x) * 8;
  f32x4 v0 = *(const f32x4*)&A[i];
  f32x4 v1 = *(const f32x4*)&A[i + 4];
  s16x8 r;
  r[0]=f2bf(v0[0]); r[1]=f2bf(v0[1]); r[2]=f2bf(v0[2]); r[3]=f2bf(v0[3]);
  r[4]=f2bf(v1[0]); r[5]=f2bf(v1[1]); r[6]=f2bf(v1[2]); r[7]=f2bf(v1[3]);
  *(s16x8*)&Ab[i] = r;
}

// W [KD][N] f32 -> Wt [N][KD] bf16
__global__ __launch_bounds__(256)
void transcvt_kernel(const float* __restrict__ W, short* __restrict__ Wt, const int N) {
  __shared__ float tile[64][65];
  const int k0 = blockIdx.x * 64, n0 = blockIdx.y * 64;
  const int t = threadIdx.x;
#pragma unroll
  for (int i = 0; i < 16; ++i) {
    const int e = i * 256 + t;
    const int k = e >> 6, n = e & 63;
    tile[n][k] = W[(size_t)(k0 + k) * N + n0 + n];
  }
  __syncthreads();
  const int nn = t >> 2, ks = (t & 3) * 16;
  s16x8 a, b;
#pragma unroll
  for (int i = 0; i < 8; i++) a[i] = f2bf(tile[nn][ks + i]);
#pragma unroll
  for (int i = 0; i < 8; i++) b[i] = f2bf(tile[nn][ks + 8 + i]);
  *(s16x8*)&Wt[(size_t)(n0 + nn) * KD + k0 + ks]     = a;
  *(s16x8*)&Wt[(size_t)(n0 + nn) * KD + k0 + ks + 8] = b;
}

// ============ gemm8: BM=256 BN=128, 4 waves, wave 128x64, ring-3, counted vmcnt, ========
// m201-style sub-phases: per K=32 tile, 2x {stage-half; ds_read; barrier; 16 MFMA}.
// Ledger identical to gemm5 (6 loads/tile, vmcnt(6), stage into buffer freed at tile start).
template<int EPI>
__global__ __launch_bounds__(256, 2)
void gemm8_kernel(const short* __restrict__ A, const short* __restrict__ Bt,
                  const float* __restrict__ bias,
                  short* __restrict__ Qb, short* __restrict__ Kb, short* __restrict__ Vb,
                  float* __restrict__ Cout)
{
  __shared__ char sm[3][24576] __attribute__((aligned(128)));
  const int KD2 = KD * 2;
  const int bid = blockIdx.x;
  const int xcd = bid & 7, idx = bid >> 3;
  const int m0 = (idx & 7) * 256;
  const int n0 = (xcd * ((EPI == 0) ? 12 : 4) + (idx >> 3)) * 128;

  const int t = threadIdx.x, lane = t & 63, c = lane & 15, g = lane >> 4;
  const int w = t >> 6, wr = w >> 1, wc = w & 1;
  const int flip = ((c >> 1) & 7) << 4;
  const int laneA = wr * 8192 + ((c * 64 + g * 16) ^ flip);
  const int laneB = 16384 + wc * 4096 + ((c * 64 + g * 16) ^ flip);

  const char* srcA[4];
  const char* srcB[2];
#pragma unroll
  for (int j = 0; j < 4; ++j) {
    const int la = j * 4096 + t * 16;
    const int ls = la ^ ((la >> 3) & 0x70);
    srcA[j] = (const char*)A + (size_t)(m0 + (ls >> 6)) * KD2 + (ls & 63);
  }
#pragma unroll
  for (int j = 0; j < 2; ++j) {
    const int la = j * 4096 + t * 16;
    const int ls = la ^ ((la >> 3) & 0x70);
    srcB[j] = (const char*)Bt + (size_t)(n0 + (ls >> 6)) * KD2 + (ls & 63);
  }

  f32x4 acc[8][4];
#pragma unroll
  for (int i = 0; i < 8; i++)
#pragma unroll
    for (int j = 0; j < 4; j++) acc[i][j] = (f32x4){0.f, 0.f, 0.f, 0.f};

#define STG_H1(S, H) do {                                     \
    const size_t ko_ = (size_t)(H) * 64;                      \
    gl_lds16(srcA[0] + ko_, sm[S] + t * 16);                  \
    gl_lds16(srcA[1] + ko_, sm[S] + 4096  + t * 16);          \
    gl_lds16(srcA[2] + ko_, sm[S] + 8192  + t * 16);          \
  } while (0)
#define STG_H2(S, H) do {                                     \
    const size_t ko_ = (size_t)(H) * 64;                      \
    gl_lds16(srcA[3] + ko_, sm[S] + 12288 + t * 16);          \
    gl_lds16(srcB[0] + ko_, sm[S] + 16384 + t * 16);          \
    gl_lds16(srcB[1] + ko_, sm[S] + 20480 + t * 16);          \
  } while (0)

  // one K=32 tile in buf S; stage tile H into buf S2 (freed at this tile's first barrier)
#define TILE8(S, S2, H, DOSTG, WN) do {                                    \
    asm volatile("s_waitcnt vmcnt(" #WN ")" ::: "memory");                 \
    __builtin_amdgcn_s_barrier();                                          \
    if (DOSTG) STG_H1(S2, H);                                              \
    const char* b_ = sm[S];                                                \
    s16x8 al_[4], bb_[4];                                                  \
    _Pragma("unroll")                                                      \
    for (int mi = 0; mi < 4; ++mi) al_[mi] = *(const s16x8*)(b_ + laneA + mi * 1024); \
    _Pragma("unroll")                                                      \
    for (int ni = 0; ni < 4; ++ni) bb_[ni] = *(const s16x8*)(b_ + laneB + ni * 1024); \
    __builtin_amdgcn_s_barrier();                                          \
    __builtin_amdgcn_s_setprio(1);                                         \
    _Pragma("unroll")                                                      \
    for (int mi = 0; mi < 4; ++mi)                                         \
      _Pragma("unroll")                                                    \
      for (int ni = 0; ni < 4; ++ni)                                       \
        acc[mi][ni] = __builtin_amdgcn_mfma_f32_16x16x32_bf16(al_[mi], bb_[ni], acc[mi][ni], 0, 0, 0); \
    __builtin_amdgcn_s_setprio(0);                                         \
    __builtin_amdgcn_s_barrier();                                          \
    if (DOSTG) STG_H2(S2, H);                                              \
    s16x8 ah_[4];                                                          \
    _Pragma("unroll")                                                      \
    for (int mi = 0; mi < 4; ++mi) ah_[mi] = *(const s16x8*)(b_ + laneA + (4 + mi) * 1024); \
    __builtin_amdgcn_s_barrier();                                          \
    __builtin_amdgcn_s_setprio(1);                                         \
    _Pragma("unroll")                                                      \
    for (int mi = 0; mi < 4; ++mi)                                         \
      _Pragma("unroll")                                                    \
      for (int ni = 0; ni < 4; ++ni)                                       \
        acc[4 + mi][ni] = __builtin_amdgcn_mfma_f32_16x16x32_bf16(ah_[mi], bb_[ni], acc[4 + mi][ni], 0, 0, 0); \
    __builtin_amdgcn_s_setprio(0);                                         \
  } while (0)

  STG_H1(0, 0); STG_H2(0, 0);
  STG_H1(1, 1); STG_H2(1, 1);
  for (int j = 0; j < 42; ++j) {
    const int h = 3 * j;
    TILE8(0, 2, h + 2, true, 6);
    TILE8(1, 0, h + 3, true, 6);
    TILE8(2, 1, h + 4, true, 6);
  }
  TILE8(0, 0, 0, false, 6);   // tile 126
  TILE8(1, 0, 0, false, 0);   // tile 127

#undef STG_H1
#undef STG_H2
#undef TILE8

  if (EPI == 0) {
#pragma unroll
    for (int ni = 0; ni < 4; ++ni) {
      const int ncol = n0 + wc * 64 + ni * 16 + c;
      const int which = ncol >> 12;
      const int h = (ncol >> 7) & 31;
      const int dcl = ncol & 127;
      short* dst = (which == 0) ? Qb : ((which == 1) ? Kb : Vb);
      const float bv = bias[ncol];
#pragma unroll
      for (int mi = 0; mi < 8; ++mi)
#pragma unroll
        for (int jj = 0; jj < 4; ++jj) {
          const int row = m0 + wr * 128 + mi * 16 + g * 4 + jj;
          dst[((size_t)h * S_LEN + row) * HD + dcl] = f2bf(acc[mi][ni][jj] + bv);
        }
    }
  } else {
#pragma unroll
    for (int ni = 0; ni < 4; ++ni) {
      const int ncol = n0 + wc * 64 + ni * 16 + c;
#pragma unroll
      for (int mi = 0; mi < 8; ++mi)
#pragma unroll
        for (int jj = 0; jj < 4; ++jj) {
          const int row = m0 + wr * 128 + mi * 16 + g * 4 + jj;
          Cout[(size_t)row * HID + ncol] = acc[mi][ni][jj];
        }
    }
  }
}

// ============ fallback GEMM (reg-staged) ============
template<int EPI, int ABF16>
__global__ __launch_bounds__(256)
void gemm_kernel(const void* __restrict__ Av, const float* __restrict__ B,
                 const float* __restrict__ bias, const int N,
                 short* __restrict__ Qb, short* __restrict__ Kb, short* __restrict__ Vb,
                 float* __restrict__ Cout)
{
  __shared__ short As[128][40];
  __shared__ short Bs[128][40];
  const int m0 = blockIdx.x * 128;
  const int nb = blockIdx.y * 128;
  const int t  = threadIdx.x;
  const int w = t >> 6, lane = t & 63, c = lane & 15, g = lane >> 4;
  const int wm = (w >> 1) * 64, wn = (w & 1) * 64;

  f32x4 acc[4][4];
#pragma unroll
  for (int i = 0; i < 4; i++)
#pragma unroll
    for (int j = 0; j < 4; j++) acc[i][j] = (f32x4){0.f, 0.f, 0.f, 0.f};

  const int ar = t >> 3;
  const int ac = (t & 7) * 4;
  const int bn = t & 127;
  const int bkq = (t >> 7) * 16;

  for (int k0 = 0; k0 < KD; k0 += 32) {
#pragma unroll
    for (int rr = 0; rr < 4; rr++) {
      const int row = rr * 32 + ar;
      if (ABF16) {
        *(s16x4*)&As[row][ac] =
          *(const s16x4*)((const short*)Av + (size_t)(m0 + row) * KD + k0 + ac);
      } else {
        f32x4 v = *(const f32x4*)((const float*)Av + (size_t)(m0 + row) * KD + k0 + ac);
        s16x4 pk;
        pk[0] = f2bf(v[0]); pk[1] = f2bf(v[1]); pk[2] = f2bf(v[2]); pk[3] = f2bf(v[3]);
        *(s16x4*)&As[row][ac] = pk;
      }
    }
    const float* pB = B + (size_t)(k0 + bkq) * N + nb + bn;
    s16x8 b0, b1;
#pragma unroll
    for (int i = 0; i < 8; i++) b0[i] = f2bf(pB[(size_t)i * N]);
#pragma unroll
    for (int i = 0; i < 8; i++) b1[i] = f2bf(pB[(size_t)(i + 8) * N]);
    *(s16x8*)&Bs[bn][bkq]     = b0;
    *(s16x8*)&Bs[bn][bkq + 8] = b1;
    __syncthreads();
    s16x8 af[4], bfr[4];
#pragma unroll
    for (int i = 0; i < 4; i++) af[i]  = *(const s16x8*)&As[wm + i * 16 + c][g * 8];
#pragma unroll
    for (int i = 0; i < 4; i++) bfr[i] = *(const s16x8*)&Bs[wn + i * 16 + c][g * 8];
#pragma unroll
    for (int mi = 0; mi < 4; mi++)
#pragma unroll
      for (int ni = 0; ni < 4; ni++)
        acc[mi][ni] = __builtin_amdgcn_mfma_f32_16x16x32_bf16(af[mi], bfr[ni], acc[mi][ni], 0, 0, 0);
    __syncthreads();
  }

  if (EPI == 0) {
    const int which = nb >> 12;
    const int h = (nb & 4095) >> 7;
    short* dst = (which == 0) ? Qb : ((which == 1) ? Kb : Vb);
#pragma unroll
    for (int ni = 0; ni < 4; ni++) {
      const int d = wn + ni * 16 + c;
      const float bv = bias[nb + d];
#pragma unroll
      for (int mi = 0; mi < 4; mi++)
#pragma unroll
        for (int j = 0; j < 4; j++) {
          const int row = m0 + wm + mi * 16 + g * 4 + j;
          dst[((size_t)h * S_LEN + row) * HD + d] = f2bf(acc[mi][ni][j] + bv);
        }
    }
  } else {
#pragma unroll
    for (int ni = 0; ni < 4; ni++) {
      const int n = nb + wn + ni * 16 + c;
#pragma unroll
      for (int mi = 0; mi < 4; mi++)
#pragma unroll
        for (int j = 0; j < 4; j++) {
          const int row = m0 + wm + mi * 16 + g * 4 + j;
          Cout[(size_t)row * N + n] = acc[mi][ni][j];
        }
    }
  }
}

// ============ RoPE ============
__global__ void rope_kernel(const int* __restrict__ positions,
                            short* __restrict__ Qb, short* __restrict__ Kb)
{
  const int s = blockIdx.x;
  const int h = blockIdx.y * 4 + threadIdx.y;
  const int d = threadIdx.x;
  const float pos = (float)positions[s];
  const float inv_freq = exp2f(-(float)d * 0.20762050593046014f);
  const float ang = pos * inv_freq;
  float sn, cs;
  sincosf(ang, &sn, &cs);
  const size_t base = ((size_t)h * S_LEN + s) * HD + d;
  const float scale = 0.08838834764831845f;
  float x1 = bf2f(Qb[base]), x2 = bf2f(Qb[base + 64]);
  Qb[base]      = f2bf((x1 * cs - x2 * sn) * scale);
  Qb[base + 64] = f2bf((x2 * cs + x1 * sn) * scale);
  x1 = bf2f(Kb[base]); x2 = bf2f(Kb[base + 64]);
  Kb[base]      = f2bf(x1 * cs - x2 * sn);
  Kb[base + 64] = f2bf(x2 * cs + x1 * sn);
}

// ============ V -> Vt [NH][HD][S] ============
__global__ __launch_bounds__(256)
void vtrans_kernel(const short* __restrict__ V, short* __restrict__ Vt)
{
  __shared__ short tile[64][72];
  const int h = blockIdx.z;
  const int s0 = blockIdx.x * 64;
  const int d0 = blockIdx.y * 64;
  const int tx = threadIdx.x & 63, ty = threadIdx.x >> 6;
  for (int r = ty; r < 64; r += 4)
    tile[r][tx] = V[((size_t)h * S_LEN + s0 + r) * HD + d0 + tx];
  __syncthreads();
  for (int r = ty; r < 64; r += 4)
    Vt[((size_t)h * HD + d0 + r) * S_LEN + s0 + tx] = tile[tx][r];
}

// ============ causal flash attention v4: paired q-panels, shared K/V fragments ============
__global__ __launch_bounds__(512)
void attn_kernel(const short* __restrict__ Q, const short* __restrict__ Kg,
                 const short* __restrict__ Vtg, short* __restrict__ attn_out)
{
  __shared__ short Ks[2][64][128];
  __shared__ short Vs[2][128][72];
  const int h = blockIdx.y;
  const int ib = blockIdx.x;
  const int q0a = ib * 128;
  const int q0b = (15 - ib) * 128;
  const int nt0 = 2 * ib + 2;
  const int nt1 = 32 - 2 * ib;
  const int t = threadIdx.x;
  const int w = t >> 6, lane = t & 63, c = lane & 15, g = lane >> 4;
  const short* Qh = Q   + (size_t)h * S_LEN * HD;
  const short* Kh = Kg  + (size_t)h * S_LEN * HD;
  const short* Vh = Vtg + (size_t)h * HD * S_LEN;

  const int krow = t >> 4, kch = t & 15;
  const int vrow = t >> 3, vch = t & 7;
  const int ksw = (kch ^ ((krow & 3) | ((krow >> 1) & 4))) * 16;

  const int rbase = (c >> 2) * 8 + (c & 3);
  const int sb = (rbase & 3) | ((rbase >> 1) & 4);
  int koff[4];
#pragma unroll
  for (int di = 0; di < 4; ++di) koff[di] = ((di * 4 + g) ^ sb) * 16;

  const int qga = q0a + w * 16 + c;
  const int qgb = q0b + w * 16 + c;
  s16x8 qfa[4], qfb[4];
#pragma unroll
  for (int di = 0; di < 4; di++) {
    qfa[di] = *(const s16x8*)&Qh[(size_t)qga * HD + di * 32 + g * 8];
    qfb[di] = *(const s16x8*)&Qh[(size_t)qgb * HD + di * 32 + g * 8];
  }

  f32x4 oa[8], ob[8];
#pragma unroll
  for (int dt = 0; dt < 8; dt++) {
    oa[dt] = (f32x4){0.f, 0.f, 0.f, 0.f};
    ob[dt] = (f32x4){0.f, 0.f, 0.f, 0.f};
  }
  float m_a = -3.0e38f, l_a = 0.f, m_b = -3.0e38f, l_b = 0.f;

#define SM_PANEL(SA, SB, SC, SD, QG, FULL, MR, LR, OARR, PB0, PB1) do {        \
    float v_[16];                                                              \
    if (FULL) {                                                                \
      _Pragma("unroll")                                                        \
      for (int j = 0; j < 4; ++j) {                                            \
        v_[j] = SA[j]; v_[4 + j] = SB[j]; v_[8 + j] = SC[j]; v_[12 + j] = SD[j]; \
      }                                                                        \
    } else {                                                                   \
      _Pragma("unroll")                                                        \
      for (int j = 0; j < 4; ++j) {                                            \
        v_[j]      = (kb + 8 * g + j          <= (QG)) ? SA[j] : -__builtin_inff(); \
        v_[4 + j]  = (kb + 8 * g + 4 + j      <= (QG)) ? SB[j] : -__builtin_inff(); \
        v_[8 + j]  = (kb + 32 + 8 * g + j     <= (QG)) ? SC[j] : -__builtin_inff(); \
        v_[12 + j] = (kb + 32 + 8 * g + 4 + j <= (QG)) ? SD[j] : -__builtin_inff(); \
      }                                                                        \
    }                                                                          \
    float mx_ = v_[0];                                                         \
    _Pragma("unroll")                                                          \
    for (int ii = 1; ii < 16; ++ii) mx_ = fmaxf(mx_, v_[ii]);                  \
    mx_ = fmaxf(mx_, __shfl_xor(mx_, 16, 64));                                 \
    mx_ = fmaxf(mx_, __shfl_xor(mx_, 32, 64));                                 \
    const float mn_ = fmaxf(MR, mx_);                                          \
    if (!__all(mn_ - MR <= 8.0f)) {                                            \
      const float al_ = __expf(MR - mn_);                                      \
      LR *= al_;                                                               \
      _Pragma("unroll")                                                        \
      for (int dt = 0; dt < 8; ++dt)                                           \
        _Pragma("unroll")                                                      \
        for (int j = 0; j < 4; ++j) OARR[dt][j] *= al_;                        \
      MR = mn_;                                                                \
    }                                                                          \
    float p_[16], rs_ = 0.f;                                                   \
    _Pragma("unroll")                                                          \
    for (int ii = 0; ii < 16; ++ii) { p_[ii] = __expf(v_[ii] - MR); rs_ += p_[ii]; } \
    rs_ += __shfl_xor(rs_, 16, 64);                                            \
    rs_ += __shfl_xor(rs_, 32, 64);                                            \
    LR += rs_;                                                                 \
    union { s16x8 v8; unsigned u[4]; } pu0_, pu1_;                             \
    pu0_.u[0] = packbf(p_[0], p_[1]);   pu0_.u[1] = packbf(p_[2], p_[3]);      \
    pu0_.u[2] = packbf(p_[4], p_[5]);   pu0_.u[3] = packbf(p_[6], p_[7]);      \
    pu1_.u[0] = packbf(p_[8], p_[9]);   pu1_.u[1] = packbf(p_[10], p_[11]);    \
    pu1_.u[2] = packbf(p_[12], p_[13]); pu1_.u[3] = packbf(p_[14], p_[15]);    \
    PB0 = pu0_.v8; PB1 = pu1_.v8;                                              \
  } while (0)

  {
#pragma unroll
    for (int i = 0; i < 2; ++i) {
      s16x8 gK = *(const s16x8*)&Kh[(size_t)(i * 32 + krow) * HD + kch * 8];
      s16x8 gV = *(const s16x8*)&Vh[(size_t)(i * 64 + vrow) * S_LEN + vch * 8];
      *(s16x8*)((char*)&Ks[0][0][0] + (i * 32 + krow) * 256 + ksw) = gK;
      *(s16x8*)&Vs[0][i * 64 + vrow][vch * 8] = gV;
    }
  }
  __syncthreads();

  for (int kt = 0; kt < nt1; kt++) {
    const int cur = kt & 1;
    const int kb = kt * 64;
    const bool do0 = (kt < nt0);
    s16x8 gK0, gK1, gV0, gV1;
    if (kt + 1 < nt1) {
      gK0 = *(const s16x8*)&Kh[(size_t)(kb + 64 + krow) * HD + kch * 8];
      gK1 = *(const s16x8*)&Kh[(size_t)(kb + 96 + krow) * HD + kch * 8];
      gV0 = *(const s16x8*)&Vh[(size_t)vrow * S_LEN + kb + 64 + vch * 8];
      gV1 = *(const s16x8*)&Vh[(size_t)(64 + vrow) * S_LEN + kb + 64 + vch * 8];
    }
    f32x4 bA = (f32x4){0,0,0,0}, bB = (f32x4){0,0,0,0};
    f32x4 bC = (f32x4){0,0,0,0}, bD = (f32x4){0,0,0,0};
    f32x4 aA = (f32x4){0,0,0,0}, aB = (f32x4){0,0,0,0};
    f32x4 aC = (f32x4){0,0,0,0}, aD = (f32x4){0,0,0,0};
    const char* kbase = (const char*)&Ks[cur][0][0] + rbase * 256;
    __builtin_amdgcn_s_setprio(1);
    if (do0) {
#pragma unroll
      for (int di = 0; di < 4; ++di) {
        const char* p = kbase + koff[di];
        s16x8 kA = *(const s16x8*)(p);
        s16x8 kB = *(const s16x8*)(p + 1024);
        s16x8 kC = *(const s16x8*)(p + 8192);
        s16x8 kD = *(const s16x8*)(p + 9216);
        bA = __builtin_amdgcn_mfma_f32_16x16x32_bf16(kA, qfb[di], bA, 0, 0, 0);
        bB = __builtin_amdgcn_mfma_f32_16x16x32_bf16(kB, qfb[di], bB, 0, 0, 0);
        bC = __builtin_amdgcn_mfma_f32_16x16x32_bf16(kC, qfb[di], bC, 0, 0, 0);
        bD = __builtin_amdgcn_mfma_f32_16x16x32_bf16(kD, qfb[di], bD, 0, 0, 0);
        aA = __builtin_amdgcn_mfma_f32_16x16x32_bf16(kA, qfa[di], aA, 0, 0, 0);
        aB = __builtin_amdgcn_mfma_f32_16x16x32_bf16(kB, qfa[di], aB, 0, 0, 0);
        aC = __builtin_amdgcn_mfma_f32_16x16x32_bf16(kC, qfa[di], aC, 0, 0, 0);
        aD = __builtin_amdgcn_mfma_f32_16x16x32_bf16(kD, qfa[di], aD, 0, 0, 0);
      }
    } else {
#pragma unroll
      for (int di = 0; di < 4; ++di) {
        const char* p = kbase + koff[di];
        s16x8 kA = *(const s16x8*)(p);
        s16x8 kB = *(const s16x8*)(p + 1024);
        s16x8 kC = *(const s16x8*)(p + 8192);
        s16x8 kD = *(const s16x8*)(p + 9216);
        bA = __builtin_amdgcn_mfma_f32_16x16x32_bf16(kA, qfb[di], bA, 0, 0, 0);
        bB = __builtin_amdgcn_mfma_f32_16x16x32_bf16(kB, qfb[di], bB, 0, 0, 0);
        bC = __builtin_amdgcn_mfma_f32_16x16x32_bf16(kC, qfb[di], bC, 0, 0, 0);
        bD = __builtin_amdgcn_mfma_f32_16x16x32_bf16(kD, qfb[di], bD, 0, 0, 0);
      }
    }
    __builtin_amdgcn_s_setprio(0);
    s16x8 pb0, pb1, pa0, pa1;
    const bool fullb = (kb + 64 <= q0b);
    SM_PANEL(bA, bB, bC, bD, qgb, fullb, m_b, l_b, ob, pb0, pb1);
    if (do0) {
      const bool fulla = (kb + 64 <= q0a);
      SM_PANEL(aA, aB, aC, aD, qga, fulla, m_a, l_a, oa, pa0, pa1);
    }
    __builtin_amdgcn_s_setprio(1);
    if (do0) {
#pragma unroll
      for (int dt = 0; dt < 8; dt++) {
        s16x8 vf0 = *(const s16x8*)&Vs[cur][dt * 16 + c][g * 8];
        s16x8 vf1 = *(const s16x8*)&Vs[cur][dt * 16 + c][32 + g * 8];
        ob[dt] = __builtin_amdgcn_mfma_f32_16x16x32_bf16(vf0, pb0, ob[dt], 0, 0, 0);
        ob[dt] = __builtin_amdgcn_mfma_f32_16x16x32_bf16(vf1, pb1, ob[dt], 0, 0, 0);
        oa[dt] = __builtin_amdgcn_mfma_f32_16x16x32_bf16(vf0, pa0, oa[dt], 0, 0, 0);
        oa[dt] = __builtin_amdgcn_mfma_f32_16x16x32_bf16(vf1, pa1, oa[dt], 0, 0, 0);
      }
    } else {
#pragma unroll
      for (int dt = 0; dt < 8; dt++) {
        s16x8 vf0 = *(const s16x8*)&Vs[cur][dt * 16 + c][g * 8];
        s16x8 vf1 = *(const s16x8*)&Vs[cur][dt * 16 + c][32 + g * 8];
        ob[dt] = __builtin_amdgcn_mfma_f32_16x16x32_bf16(vf0, pb0, ob[dt], 0, 0, 0);
        ob[dt] = __builtin_amdgcn_mfma_f32_16x16x32_bf16(vf1, pb1, ob[dt], 0, 0, 0);
      }
    }
    __builtin_amdgcn_s_setprio(0);
    __syncthreads();
    if (kt + 1 < nt1) {
      *(s16x8*)((char*)&Ks[cur ^ 1][0][0] + krow * 256 + ksw)        = gK0;
      *(s16x8*)((char*)&Ks[cur ^ 1][0][0] + (32 + krow) * 256 + ksw) = gK1;
      *(s16x8*)&Vs[cur ^ 1][vrow][vch * 8]      = gV0;
      *(s16x8*)&Vs[cur ^ 1][64 + vrow][vch * 8] = gV1;
    }
    __syncthreads();
  }
#undef SM_PANEL

  const float inv_b = 1.0f / l_b;
  const float inv_a = 1.0f / l_a;
#pragma unroll
  for (int dt = 0; dt < 8; dt++) {
    s16x4 pkb, pka;
#pragma unroll
    for (int j = 0; j < 4; j++) {
      pkb[j] = f2bf(ob[dt][j] * inv_b);
      pka[j] = f2bf(oa[dt][j] * inv_a);
    }
    *(s16x4*)&attn_out[(size_t)qgb * HID + h * HD + dt * 16 + g * 4] = pkb;
    *(s16x4*)&attn_out[(size_t)qga * HID + h * HD + dt * 16 + g * 4] = pka;
  }
}

extern "C" void kernel_launch(void* const* d_in, const int* in_sizes, int n_in,
                              void* d_out, int out_size, void* d_ws, size_t ws_size,
                              hipStream_t stream)
{
  const int*   positions = (const int*)d_in[0];
  const float* hidden    = (const float*)d_in[1];
  const float* w_qkv     = (const float*)d_in[2];
  const float* b_qkv     = (const float*)d_in[3];
  const float* w_o       = (const float*)d_in[4];
  float* out = (float*)d_out;

  char* ws = (char*)d_ws;
  const size_t MB = (size_t)1 << 20;

  if (ws_size >= 224 * MB) {
    short* Ah    = (short*)(ws);                 // 16 MB  bf16 [S][KD]
    short* Wqt   = (short*)(ws + 16 * MB);       // 96 MB  bf16 [3*HID][KD]
    short* Wot   = (short*)(ws + 112 * MB);      // 32 MB  bf16 [HID][KD]
    short* Qb    = (short*)(ws + 144 * MB);      // 16 MB
    short* Kb    = (short*)(ws + 160 * MB);      // 16 MB
    short* Vb    = (short*)(ws + 176 * MB);      // 16 MB
    short* Vt    = (short*)(ws + 192 * MB);      // 16 MB
    short* attnb = (short*)(ws + 208 * MB);      // 16 MB  bf16 [S][HID]

    cvt_kernel<<<4096, 256, 0, stream>>>(hidden, Ah);
    transcvt_kernel<<<dim3(KD / 64, 3 * HID / 64), 256, 0, stream>>>(w_qkv, Wqt, 3 * HID);
    transcvt_kernel<<<dim3(KD / 64, HID / 64), 256, 0, stream>>>(w_o, Wot, HID);
    gemm8_kernel<0><<<768, 256, 0, stream>>>(Ah, Wqt, b_qkv, Qb, Kb, Vb, nullptr);
    rope_kernel<<<dim3(S_LEN, NH / 4), dim3(64, 4), 0, stream>>>(positions, Qb, Kb);
    vtrans_kernel<<<dim3(S_LEN / 64, HD / 64, NH), 256, 0, stream>>>(Vb, Vt);
    attn_kernel<<<dim3(8, NH), 512, 0, stream>>>(Qb, Kb, Vt, attnb);
    gemm8_kernel<1><<<256, 256, 0, stream>>>(attnb, Wot, nullptr,
                                             nullptr, nullptr, nullptr, out);
  } else {
    short* Qb    = (short*)(ws);
    short* Kb    = (short*)(ws + 16 * MB);
    short* Vb    = (short*)(ws + 32 * MB);
    short* Vt    = (short*)(ws + 48 * MB);
    short* attnb = (short*)(ws + 64 * MB);

    gemm_kernel<0, 0><<<dim3(16, 96), 256, 0, stream>>>(hidden, w_qkv, b_qkv, 3 * HID,
                                                        Qb, Kb, Vb, nullptr);
    rope_kernel<<<dim3(S_LEN, NH / 4), dim3(64, 4), 0, stream>>>(positions, Qb, Kb);
    vtrans_kernel<<<dim3(S_LEN / 64, HD / 64, NH), 256, 0, stream>>>(Vb, Vt);
    attn_kernel<<<dim3(8, NH), 512, 0, stream>>>(Qb, Kb, Vt, attnb);
    gemm_kernel<1, 1><<<dim3(16, 32), 256, 0, stream>>>(attnb, w_o, nullptr, HID,
                                                        nullptr, nullptr, nullptr, out);
  }
}